// Round 1
// baseline (299.687 us; speedup 1.0000x reference)
//
#include <hip/hip_runtime.h>
#include <cmath>

// HungarianMatcher cost matrix: C[bs, Q, T] = 5*L1 + 1*focal_class + 2*(-GIoU)
// BS=16, Q=1500, K=256, NT=150 -> N=24000 queries, T=2400 targets.
// Store-BW bound: 230.4 MB output. Focal class cost computed once per
// (query, class) into a 256-entry LDS table (K == blockDim), gathered per target.

namespace {
constexpr int kBS = 16, kQ = 1500, kK = 256, kNT = 150;
constexpr int kT  = kBS * kNT;   // 2400 targets
constexpr int kN  = kBS * kQ;    // 24000 queries
constexpr int kNPB = 8;          // queries per block (24000 / 8 = 3000 blocks)
constexpr int kGroups = 3;       // per-thread float4 output groups: ceil(600/256)
constexpr float kAlpha = 0.25f;
constexpr float kEps   = 1e-8f;
}

__global__ __launch_bounds__(256)
void matcher_cost_kernel(const float* __restrict__ logits,   // [N, 256]
                         const float* __restrict__ pboxes,   // [N, 4] cxcywh
                         const float* __restrict__ tboxes,   // [T, 4] cxcywh
                         const int*   __restrict__ tids,     // [T]
                         float* __restrict__ out)            // [N, T]
{
    __shared__ float s_cls[kK];   // focal class cost for current query, per class
    const int tid = threadIdx.x;
    const int n0  = blockIdx.x * kNPB;

    // ---- Stage all 2400 targets into registers (once per block) ----
    // Thread owns float4-groups g: targets t = 4*(tid + 256*g) + e, e in 0..3.
    float tcx[kGroups][4], tcy[kGroups][4], twd[kGroups][4], tht[kGroups][4];
    int   tcl[kGroups][4];
    bool  valid[kGroups];
    const float4* tb4 = reinterpret_cast<const float4*>(tboxes);
    const int4*   ti4 = reinterpret_cast<const int4*>(tids);
#pragma unroll
    for (int g = 0; g < kGroups; ++g) {
        const int q4 = tid + 256 * g;      // float4-group index, valid if < 600
        valid[g] = (q4 < kT / 4);
        if (valid[g]) {
#pragma unroll
            for (int e = 0; e < 4; ++e) {
                const float4 b = tb4[q4 * 4 + e];   // one target box (cx,cy,w,h)
                tcx[g][e] = b.x; tcy[g][e] = b.y; twd[g][e] = b.z; tht[g][e] = b.w;
            }
            const int4 c = ti4[q4];
            tcl[g][0] = c.x; tcl[g][1] = c.y; tcl[g][2] = c.z; tcl[g][3] = c.w;
        }
    }

    // ---- Loop over this block's queries ----
    for (int i = 0; i < kNPB; ++i) {
        const int n = n0 + i;

        // Focal classification cost for class `tid` of query n:
        //   pos - neg = -a*(1-p)^2*log(p+eps) + (1-a)*p^2*log(1-p+eps)
        const float x   = logits[n * kK + tid];
        const float p   = __builtin_amdgcn_rcpf(1.0f + __expf(-x));
        const float omp = 1.0f - p;
        const float ccls = -kAlpha * omp * omp * __logf(p + kEps)
                         + (1.0f - kAlpha) * p * p * __logf(omp + kEps);

        __syncthreads();            // protect previous iteration's table readers
        s_cls[tid] = ccls;

        // Pred box (block-uniform -> scalar loads)
        const float pcx = pboxes[n * 4 + 0];
        const float pcy = pboxes[n * 4 + 1];
        const float pw  = pboxes[n * 4 + 2];
        const float ph  = pboxes[n * 4 + 3];
        const float px1 = pcx - 0.5f * pw, py1 = pcy - 0.5f * ph;
        const float px2 = pcx + 0.5f * pw, py2 = pcy + 0.5f * ph;
        const float parea = pw * ph;

        __syncthreads();            // table ready

        float4* orow = reinterpret_cast<float4*>(out + (size_t)n * kT);
#pragma unroll
        for (int g = 0; g < kGroups; ++g) {
            if (!valid[g]) continue;
            float res[4];
#pragma unroll
            for (int e = 0; e < 4; ++e) {
                const float bcx = tcx[g][e], bcy = tcy[g][e];
                const float bw  = twd[g][e], bh  = tht[g][e];

                // L1 cost in cxcywh space
                const float cb = fabsf(pcx - bcx) + fabsf(pcy - bcy)
                               + fabsf(pw - bw)  + fabsf(ph - bh);

                // GIoU in xyxy space
                const float tx1 = bcx - 0.5f * bw, ty1 = bcy - 0.5f * bh;
                const float tx2 = bcx + 0.5f * bw, ty2 = bcy + 0.5f * bh;
                const float tarea = bw * bh;
                const float iw = fmaxf(fminf(px2, tx2) - fmaxf(px1, tx1), 0.0f);
                const float ih = fmaxf(fminf(py2, ty2) - fmaxf(py1, ty1), 0.0f);
                const float inter = iw * ih;
                const float uni   = parea + tarea - inter;
                const float ew = fmaxf(fmaxf(px2, tx2) - fminf(px1, tx1), 0.0f);
                const float eh = fmaxf(fmaxf(py2, ty2) - fminf(py1, ty1), 0.0f);
                const float earea = ew * eh;
                const float iou  = inter * __builtin_amdgcn_rcpf(uni);
                const float giou = iou - (earea - uni) * __builtin_amdgcn_rcpf(earea);

                const float cc = s_cls[tcl[g][e]];   // LDS gather at target class
                res[e] = 5.0f * cb + cc - 2.0f * giou;
            }
            const float4 v = make_float4(res[0], res[1], res[2], res[3]);
            orow[tid + 256 * g] = v;                 // coalesced 16B/lane store
        }
    }
}

extern "C" void kernel_launch(void* const* d_in, const int* in_sizes, int n_in,
                              void* d_out, int out_size, void* d_ws, size_t ws_size,
                              hipStream_t stream) {
    const float* logits = (const float*)d_in[0];   // [16,1500,256]
    const float* pboxes = (const float*)d_in[1];   // [16,1500,4]
    const float* tboxes = (const float*)d_in[2];   // [2400,4]
    const int*   tids   = (const int*)d_in[3];     // [2400]
    float* out = (float*)d_out;                    // [16,1500,2400] fp32

    dim3 grid(kN / kNPB);   // 3000 blocks
    dim3 block(256);
    hipLaunchKernelGGL(matcher_cost_kernel, grid, block, 0, stream,
                       logits, pboxes, tboxes, tids, out);
}

// Round 2
// 274.732 us; speedup vs baseline: 1.0908x; 1.0908x over previous
//
#include <hip/hip_runtime.h>
#include <hip/hip_fp16.h>
#include <cmath>

// HungarianMatcher cost matrix C[16,1500,2400] = 5*L1 + focal_class + 2*(-GIoU)
// Store-BW floor ~37us (230MB out); VALU floor ~30us. Structure:
//  - block = 256 thr, owns 16 queries x 1024-target tile (grid 1500 x 3)
//  - targets staged in LDS SoA (float2 cxy / float2 wh / u8 class)
//  - focal class cost for all 16 queries precomputed into fp16 LDS table
//    (one table write per (q,class), gathered per (q,target)) -> single barrier
//  - per-element: enclose = pw+bw-overlap identity; one v_rcp of uni*earea
//  - stores: dword per element, lanes consecutive -> coalesced 256B/instr

namespace {
constexpr int kBS = 16, kQ = 1500, kK = 256, kNT = 150;
constexpr int kT  = kBS * kNT;   // 2400 targets
constexpr int kN  = kBS * kQ;    // 24000 queries
constexpr int kQB = 16;          // queries per block
constexpr int kTT = 1024;        // target tile (tiles: 1024,1024,352)
constexpr int kTiles = 3;
constexpr float kAlpha = 0.25f;
constexpr float kEps   = 1e-8f;
}

__global__ __launch_bounds__(256, 4)
void matcher_cost_kernel(const float* __restrict__ logits,   // [N,256]
                         const float* __restrict__ pboxes,   // [N,4] cxcywh
                         const float* __restrict__ tboxes,   // [T,4] cxcywh
                         const int*   __restrict__ tids,     // [T]
                         float* __restrict__ out)            // [N,T]
{
    __shared__ float2 s_cxy[kTT];            // 8 KB
    __shared__ float2 s_wh[kTT];             // 8 KB
    __shared__ unsigned char s_cid[kTT];     // 1 KB
    __shared__ __half s_fcl[kQB][kK];        // 8 KB  focal cost per (query,class)

    const int tid  = threadIdx.x;
    const int n0   = blockIdx.x * kQB;
    const int t0   = blockIdx.y * kTT;
    const int tsz  = min(kTT, kT - t0);

    // ---- stage target tile into LDS (SoA) ----
    const float4* tb4 = reinterpret_cast<const float4*>(tboxes);
    for (int j = tid; j < tsz; j += 256) {
        const float4 b = tb4[t0 + j];
        s_cxy[j] = make_float2(b.x, b.y);
        s_wh[j]  = make_float2(b.z, b.w);
        s_cid[j] = (unsigned char)tids[t0 + j];
    }

    // ---- focal class-cost table for this block's 16 queries ----
    for (int q = 0; q < kQB; ++q) {
        const float x   = logits[(n0 + q) * kK + tid];
        const float p   = __builtin_amdgcn_rcpf(1.0f + __expf(-x));
        const float omp = 1.0f - p;
        const float cc  = -kAlpha * omp * omp * __logf(p + kEps)
                        + (1.0f - kAlpha) * p * p * __logf(omp + kEps);
        s_fcl[q][tid] = __float2half(cc);
    }

    __syncthreads();   // the only barrier; LDS read-only below

    // ---- main loop: 16 queries x 4 elements/thread, no barriers ----
    for (int q = 0; q < kQB; ++q) {
        const int n = n0 + q;
        const float pcx = pboxes[n * 4 + 0];
        const float pcy = pboxes[n * 4 + 1];
        const float pw  = pboxes[n * 4 + 2];
        const float ph  = pboxes[n * 4 + 3];
        const float px1 = pcx - 0.5f * pw, px2 = pcx + 0.5f * pw;
        const float py1 = pcy - 0.5f * ph, py2 = pcy + 0.5f * ph;
        const float parea = pw * ph;
        float* __restrict__ row = out + (size_t)n * kT + t0;

        auto body = [&](int t) {
            const float2 cxy = s_cxy[t];
            const float2 wh  = s_wh[t];
            const float bcx = cxy.x, bcy = cxy.y, bw = wh.x, bh = wh.y;
            const float cc = __half2float(s_fcl[q][s_cid[t]]);
            // L1 cost (cxcywh space)
            const float cb = fabsf(pcx - bcx) + fabsf(pcy - bcy)
                           + fabsf(pw - bw)  + fabsf(ph - bh);
            // overlap; enclose via identity ew = pw+bw-ow
            const float tx1 = bcx - 0.5f * bw, tx2 = bcx + 0.5f * bw;
            const float ty1 = bcy - 0.5f * bh, ty2 = bcy + 0.5f * bh;
            const float ow = fminf(px2, tx2) - fmaxf(px1, tx1);
            const float oh = fminf(py2, ty2) - fmaxf(py1, ty1);
            const float iw = fmaxf(ow, 0.0f), ih = fmaxf(oh, 0.0f);
            const float ew = (pw + bw) - ow,  eh = (ph + bh) - oh;
            const float inter = iw * ih;
            const float uni   = parea + bw * bh - inter;
            const float earea = ew * eh;
            // giou = inter/uni - 1 + uni/earea
            // out  = 5cb + (cc+2) - 2*(inter*earea + uni*uni)/(uni*earea)
            const float r    = __builtin_amdgcn_rcpf(uni * earea);
            const float frac = fmaf(uni, uni, inter * earea) * r;
            row[t] = fmaf(5.0f, cb, cc + 2.0f) - 2.0f * frac;
        };

        if (tsz == kTT) {
#pragma unroll
            for (int e = 0; e < 4; ++e) body(tid + 256 * e);
        } else {
            for (int t = tid; t < tsz; t += 256) body(t);
        }
    }
}

extern "C" void kernel_launch(void* const* d_in, const int* in_sizes, int n_in,
                              void* d_out, int out_size, void* d_ws, size_t ws_size,
                              hipStream_t stream) {
    const float* logits = (const float*)d_in[0];   // [16,1500,256]
    const float* pboxes = (const float*)d_in[1];   // [16,1500,4]
    const float* tboxes = (const float*)d_in[2];   // [2400,4]
    const int*   tids   = (const int*)d_in[3];     // [2400]
    float* out = (float*)d_out;                    // [16,1500,2400] fp32

    dim3 grid(kN / kQB, kTiles);   // 1500 x 3
    dim3 block(256);
    hipLaunchKernelGGL(matcher_cost_kernel, grid, block, 0, stream,
                       logits, pboxes, tboxes, tids, out);
}